// Round 11
// baseline (135.636 us; speedup 1.0000x reference)
//
#include <hip/hip_runtime.h>
#include <hip/hip_bf16.h>
#include <cstdint>

// Problem: B=32, S=1024, H_IN=1024, H=1024
// scores[b,s] = sum_h tanh( enc[b,s,:]·W1_enc[h,:] + hidden[b,:]·W1_hid[h,:] + b1[h] ) * W2[h]
// out[b,0,s] = softmax_s( mask ? -inf : scores )    (b2 is softmax-shift-invariant)
//
// Round 11 (4 launches): prep_k + conv_k (both r10, linear layouts; conv pads to 256)
// -> gemm_r4: 256x256 tile, BK=32, 4-deep LDS ring (4 x 32KB slots), per-K-step
// fine interleave {vmcnt(8) counted -> barrier -> STAGE(kt+3) -> 12 ds_read ->
// setprio 32 MFMA}, staged tiles get 3 compute-steps of latency cover.
// LDS swizzle via source-XOR at stage (chunk cp^(row&3) in each 32-elem segment),
// read applies same XOR (involution; rule 21 both-sides). -> softmax_k (r10).
//
// vmcnt ledger (4 gload_lds per STAGE): at gate of step kt, outstanding =
// stages of kt+1 (issued step kt-2) + kt+2 (kt-1) = 8 -> vmcnt(8) proves kt landed.
// Overwrite: STAGE(kt+3) targets slot (kt-1)&3 whose last ds_reads finished in
// step kt-1 (program order), separated by this step's barrier.

#define NKT32 32

typedef short  s16x8 __attribute__((ext_vector_type(8)));
typedef float  f32x4 __attribute__((ext_vector_type(4)));
typedef unsigned int u32;
typedef unsigned short u16;
typedef unsigned long long u64;

__device__ static inline u32 f2bf(float f) {            // f32 -> bf16 (RNE)
    u32 u = __float_as_uint(f);
    return (u + 0x7fffu + ((u >> 16) & 1u)) >> 16;
}
__device__ static inline u32 pk2(float a, float b) {
    return f2bf(a) | (f2bf(b) << 16);
}

__device__ static inline void gload_lds16(const void* g, void* l) {
    __builtin_amdgcn_global_load_lds(
        (const __attribute__((address_space(1))) u32*)g,
        (__attribute__((address_space(3))) u32*)l, 16, 0, 0);
}

// ---------------- prep: pack W1_enc (linear) + hv + mask compaction + zero scores ----------------
__global__ __launch_bounds__(256) void prep_k(const float* __restrict__ W1,
                                              const float* __restrict__ hidden,
                                              const float* __restrict__ b1,
                                              const void*  __restrict__ maskv,
                                              u16*   __restrict__ Wb,
                                              float* __restrict__ hv,
                                              int*   __restrict__ sidx,
                                              int*   __restrict__ cnt,
                                              float* __restrict__ scores) {
    const int bx = blockIdx.x, t = threadIdx.x;
    const int wid = t >> 6, lane = t & 63;
    __shared__ int sflag[4];

    if (bx < 512) {
        // pack W1_enc to bf16, LINEAR [n][k]
        const int i = bx * 256 + t;                    // 16B-out-chunk id, 0..131071
        const int n = i >> 7, gc = i & 127;
        const float4 v0 = *(const float4*)(W1 + (size_t)n * 2048 + gc * 8);
        const float4 v1 = *(const float4*)(W1 + (size_t)n * 2048 + gc * 8 + 4);
        uint4 o; o.x = pk2(v0.x, v0.y); o.y = pk2(v0.z, v0.w);
        o.z = pk2(v1.x, v1.y); o.w = pk2(v1.z, v1.w);
        *(uint4*)(Wb + (size_t)n * 1024 + gc * 8) = o;
    } else if (bx < 768) {
        // hv[b][h] = hidden[b,:]·W1_hid[h,:] + b1[h]
        const int h = (bx - 512) * 4 + wid;
        const float4* wrow = (const float4*)(W1 + (size_t)h * 2048 + 1024);
        float4 w[4];
#pragma unroll
        for (int q = 0; q < 4; q++) w[q] = wrow[lane + 64 * q];
        for (int b = 0; b < 32; b++) {
            const float4* hb = (const float4*)(hidden + (size_t)b * 1024);
            float p = 0.f;
#pragma unroll
            for (int q = 0; q < 4; q++) {
                float4 x = hb[lane + 64 * q];
                p = fmaf(w[q].x, x.x, fmaf(w[q].y, x.y, fmaf(w[q].z, x.z, fmaf(w[q].w, x.w, p))));
            }
#pragma unroll
            for (int off = 1; off < 64; off <<= 1) p += __shfl_xor(p, off);
            if (lane == 0) hv[(size_t)b * 1024 + h] = p + b1[h];
        }
    } else if (bx < 776) {
        // mask dtype detect + per-batch stable compaction of unmasked s
        const u32* mw = (const u32*)maskv;
        int f = 0;
#pragma unroll
        for (int j = 0; j < 32; j++) f |= (mw[t * 32 + j] > 1u) ? 1 : 0;
        const int anyf = __any(f);
        if (lane == 0) sflag[wid] = anyf;
        __syncthreads();
        const int bytemode = sflag[0] | sflag[1] | sflag[2] | sflag[3];

        const int b = (bx - 768) * 4 + wid;
        int base = 0;
        for (int c = 0; c < 16; c++) {
            const int s = c * 64 + lane;
            int m;
            if (bytemode) m = ((const unsigned char*)maskv)[(size_t)b * 1024 + s];
            else          m = ((const int*)maskv)[(size_t)b * 1024 + s];
            const u64 bal = __ballot(m == 0);
            if (m == 0) {
                const int off = (int)__popcll(bal & ((1ull << lane) - 1ull));
                sidx[(size_t)b * 1024 + base + off] = s;
            }
            base += (int)__popcll(bal);
        }
        if (lane == 0) cnt[b] = base;
        for (int j = base + lane; j < 1024; j += 64) sidx[(size_t)b * 1024 + j] = 0;
    } else {
        // zero scores
        const int i = (bx - 776) * 256 + t;
        ((float4*)scores)[i] = make_float4(0.f, 0.f, 0.f, 0.f);
    }
}

// ---------------- gather-convert compacted enc rows to bf16, LINEAR, 256-padded ----------------
// 8192 blocks, XCD-aligned to the gemm's batch->XCD map. 4 rows per block.
__global__ __launch_bounds__(256) void conv_k(const float* __restrict__ enc,
                                              const int* __restrict__ sidx,
                                              const int* __restrict__ cnt,
                                              u16* __restrict__ encC) {
    const int bid = blockIdx.x, t = threadIdx.x;
    const int xcd = bid & 7, w = bid >> 3;             // w 0..1023
    const int b = xcd * 4 + (w >> 8);                  // batches 4X..4X+3 on XCD X
    const int j0 = (w & 255) * 4;
    const int c = cnt[b];
    if (j0 >= ((c + 255) & ~255)) return;              // pad to BM=256 tiles
#pragma unroll
    for (int r = 0; r < 4; r++) {
        const int j = j0 + r;
        const int s = (j < c) ? sidx[(size_t)b * 1024 + j] : 0;
        const float4 v = ((const float4*)(enc + ((size_t)s * 32 + b) * 1024))[t];
        uint2 o; o.x = pk2(v.x, v.y); o.y = pk2(v.z, v.w);
        *(uint2*)(encC + ((size_t)b * 1024 + j) * 1024 + t * 4) = o;
    }
}

// ---------------- GEMM: 256x256, BK=32, 4-deep ring, fine per-step interleave ----------------
// 512 threads = 8 waves (wm 0..1 x wn 0..3); per-wave out 128x64, acc[8][4].
__global__ __launch_bounds__(512, 2) void gemm_r4(
    const u16* __restrict__ encC,       // [32][1024][1024] bf16, linear compacted rows
    const u16* __restrict__ Wb,         // [1024][1024] bf16, linear
    const int* __restrict__ sidx,
    const int* __restrict__ cnt,
    const float* __restrict__ hv,
    const float* __restrict__ W2,
    float*      __restrict__ scores)    // [32][1024] f32, pre-zeroed, atomics
{
    __shared__ u16 lds[4 * 16384];      // 4 slots x (A 8192 + B 8192 u16) = 128 KB

    const int tid = threadIdx.x;
    const int bid = blockIdx.x;         // 512 blocks
    // XCD map: strips of one batch stay on the batch's conv XCD
    const int xcd = bid & 7, idx = bid >> 3;           // idx 0..63
    const int strip = xcd * 16 + (idx >> 2);           // 0..127 = b*4+mt
    const int nt = idx & 3;
    const int b = strip >> 2, mt = strip & 3;
    const int c = cnt[b];
    if (mt * 256 >= c) return;

    const u16* abase = encC + ((size_t)b * 1024 + mt * 256) * 1024;
    const u16* bbase = Wb + (size_t)(nt * 256) * 1024;

    const int wid = tid >> 6, lane = tid & 63;
    const int wm = wid >> 2, wn = wid & 3;
    const int lhi = lane >> 4, llo = lane & 15;

    f32x4 acc[8][4] = {};

    // stage: 1024 chunks/operand; thread stages cix = j*512+tid; row=cix>>2, phys chunk=cix&3;
    // source uses logical chunk (cp ^ (row&3))  [involution with the read XOR]
#define STAGE(KT)                                                                \
    {                                                                            \
        u16* Asl = &lds[((KT) & 3) * 16384];                                     \
        u16* Bsl = Asl + 8192;                                                   \
        const size_t ko = (size_t)(KT) * 32;                                     \
        _Pragma("unroll")                                                        \
        for (int j = 0; j < 2; j++) {                                            \
            const int cix = j * 512 + tid;                                       \
            const int row = cix >> 2, cp = cix & 3;                              \
            const int lc = cp ^ (row & 3);                                       \
            gload_lds16(abase + (size_t)row * 1024 + ko + lc * 8, Asl + cix * 8);\
            gload_lds16(bbase + (size_t)row * 1024 + ko + lc * 8, Bsl + cix * 8);\
        }                                                                        \
    }

#define COMPUTE(KT)                                                              \
    {                                                                            \
        const u16* Asl = &lds[((KT) & 3) * 16384];                               \
        const u16* Bsl = Asl + 8192;                                             \
        s16x8 bf[4], af[8];                                                      \
        _Pragma("unroll")                                                        \
        for (int fj = 0; fj < 4; fj++) {                                         \
            const int row = wn * 64 + fj * 16 + llo;                             \
            const int cp = lhi ^ (row & 3);                                      \
            bf[fj] = *(const s16x8*)&Bsl[row * 32 + cp * 8];                     \
        }                                                                        \
        _Pragma("unroll")                                                        \
        for (int fi = 0; fi < 8; fi++) {                                         \
            const int row = wm * 128 + fi * 16 + llo;                            \
            const int cp = lhi ^ (row & 3);                                      \
            af[fi] = *(const s16x8*)&Asl[row * 32 + cp * 8];                     \
        }                                                                        \
        __builtin_amdgcn_s_setprio(1);                                           \
        _Pragma("unroll")                                                        \
        for (int fi = 0; fi < 8; fi++)                                           \
            _Pragma("unroll")                                                    \
            for (int fj = 0; fj < 4; fj++)                                       \
                acc[fi][fj] = __builtin_amdgcn_mfma_f32_16x16x32_bf16(           \
                    af[fi], bf[fj], acc[fi][fj], 0, 0, 0);                       \
        __builtin_amdgcn_s_setprio(0);                                           \
    }

    // prologue: 3 tiles in flight
    STAGE(0); STAGE(1); STAGE(2);

    // steady state: kt = 0..27  (stages kt+3 = 3..30)
    for (int kt = 0; kt < 28; kt++) {
        asm volatile("s_waitcnt vmcnt(8)" ::: "memory");   // kt landed; kt+1,kt+2 in flight
        __builtin_amdgcn_s_barrier();
        STAGE(kt + 3);                                     // slot (kt-1)&3, freed last step
        COMPUTE(kt);
    }
    // kt = 28: stage the last tile (31)
    asm volatile("s_waitcnt vmcnt(8)" ::: "memory");
    __builtin_amdgcn_s_barrier();
    STAGE(31);
    COMPUTE(28);
    // kt = 29: outstanding = 30,31 = 8
    asm volatile("s_waitcnt vmcnt(8)" ::: "memory");
    __builtin_amdgcn_s_barrier();
    COMPUTE(29);
    // kt = 30: outstanding = 31 = 4
    asm volatile("s_waitcnt vmcnt(4)" ::: "memory");
    __builtin_amdgcn_s_barrier();
    COMPUTE(30);
    // kt = 31
    asm volatile("s_waitcnt vmcnt(0)" ::: "memory");
    __builtin_amdgcn_s_barrier();
    COMPUTE(31);
#undef STAGE
#undef COMPUTE

    // epilogue: tanh(acc + hv) · w2, reduce over 16 llo-cols x 4 fj (wave's 64 n-cols),
    // scatter-atomic into scores (4 wn-waves accumulate per row)
    const float* hvb = hv + (size_t)b * 1024;
    float hvv[4], w2v[4];
#pragma unroll
    for (int fj = 0; fj < 4; fj++) {
        const int n = nt * 256 + wn * 64 + fj * 16 + llo;
        hvv[fj] = hvb[n];
        w2v[fj] = W2[n];
    }
#pragma unroll
    for (int fi = 0; fi < 8; fi++) {
#pragma unroll
        for (int r = 0; r < 4; r++) {
            float sum = 0.f;
#pragma unroll
            for (int fj = 0; fj < 4; fj++) {
                const float x = acc[fi][fj][r] + hvv[fj];
                const float e = __expf(2.f * x);
                const float t = 1.f - 2.f / (e + 1.f);   // tanh(x)
                sum = fmaf(t, w2v[fj], sum);
            }
            sum += __shfl_xor(sum, 1);
            sum += __shfl_xor(sum, 2);
            sum += __shfl_xor(sum, 4);
            sum += __shfl_xor(sum, 8);
            if (llo == 0) {
                const int j = mt * 256 + wm * 128 + fi * 16 + lhi * 4 + r;
                if (j < c) {
                    const int s = sidx[(size_t)b * 1024 + j];
                    atomicAdd(&scores[(size_t)b * 1024 + s], sum);
                }
            }
        }
    }
}

// ---------------- masked softmax per row b, mask dtype auto-detected ----------------
__global__ __launch_bounds__(256) void softmax_k(const float* __restrict__ scores,
                                                 const void* __restrict__ maskv,
                                                 float* __restrict__ out) {
    const int b = blockIdx.x, t = threadIdx.x;
    const int wid = t >> 6, lane = t & 63;
    const u32* mw = (const u32*)maskv;
    int f = 0;
#pragma unroll
    for (int j = 0; j < 32; j++) f |= (mw[t * 32 + j] > 1u) ? 1 : 0;
    __shared__ int sflag[4];
    const int anyf = __any(f);
    if (lane == 0) sflag[wid] = anyf;
    __syncthreads();
    const int bytemode = sflag[0] | sflag[1] | sflag[2] | sflag[3];

    int m0, m1, m2, m3;
    if (bytemode) {
        const uchar4 mk = ((const uchar4*)((const unsigned char*)maskv + (size_t)b * 1024))[t];
        m0 = mk.x; m1 = mk.y; m2 = mk.z; m3 = mk.w;
    } else {
        const int4 mk = ((const int4*)((const int*)maskv + (size_t)b * 1024))[t];
        m0 = mk.x; m1 = mk.y; m2 = mk.z; m3 = mk.w;
    }
    const float4 sc = ((const float4*)(scores + (size_t)b * 1024))[t];
    const float v0 = m0 ? -1e30f : sc.x;
    const float v1 = m1 ? -1e30f : sc.y;
    const float v2 = m2 ? -1e30f : sc.z;
    const float v3 = m3 ? -1e30f : sc.w;
    float mx = fmaxf(fmaxf(v0, v1), fmaxf(v2, v3));
#pragma unroll
    for (int off = 1; off < 64; off <<= 1) mx = fmaxf(mx, __shfl_xor(mx, off));
    __shared__ float redm[4], reds[4];
    if (lane == 0) redm[wid] = mx;
    __syncthreads();
    mx = fmaxf(fmaxf(redm[0], redm[1]), fmaxf(redm[2], redm[3]));
    const float e0 = m0 ? 0.f : __expf(v0 - mx);
    const float e1 = m1 ? 0.f : __expf(v1 - mx);
    const float e2 = m2 ? 0.f : __expf(v2 - mx);
    const float e3 = m3 ? 0.f : __expf(v3 - mx);
    float s = e0 + e1 + e2 + e3;
#pragma unroll
    for (int off = 1; off < 64; off <<= 1) s += __shfl_xor(s, off);
    if (lane == 0) reds[wid] = s;
    __syncthreads();
    s = reds[0] + reds[1] + reds[2] + reds[3];
    const float inv = 1.f / s;
    float4 o; o.x = e0 * inv; o.y = e1 * inv; o.z = e2 * inv; o.w = e3 * inv;
    ((float4*)(out + (size_t)b * 1024))[t] = o;
}

extern "C" void kernel_launch(void* const* d_in, const int* in_sizes, int n_in,
                              void* d_out, int out_size, void* d_ws, size_t ws_size,
                              hipStream_t stream) {
    const float* hidden = (const float*)d_in[0];
    const float* enc    = (const float*)d_in[1];           // (S,B,H_IN) f32
    const void*  mask   = d_in[2];
    const float* W1 = (const float*)d_in[3];               // (H, H_IN+H) f32
    const float* b1 = (const float*)d_in[4];
    const float* W2 = (const float*)d_in[5];
    float* out = (float*)d_out;

    char* ws = (char*)d_ws;
    float* ws_scores = (float*)ws;                          // 128 KB
    float* ws_hv     = (float*)(ws + (128u << 10));         // 128 KB
    u16*   ws_Wb     = (u16*)(ws + (256u << 10));           // 2 MB
    int*   ws_cnt    = (int*)(ws + (2304u << 10));          // 128 B
    int*   ws_sidx   = (int*)(ws + (2432u << 10));          // 128 KB
    u16*   ws_encC   = (u16*)(ws + (4096u << 10));          // 64 MB

    prep_k<<<808, 256, 0, stream>>>(W1, hidden, b1, mask, ws_Wb, ws_hv, ws_sidx, ws_cnt, ws_scores);
    conv_k<<<8192, 256, 0, stream>>>(enc, ws_sidx, ws_cnt, ws_encC);
    gemm_r4<<<512, 512, 0, stream>>>(ws_encC, ws_Wb, ws_sidx, ws_cnt, ws_hv, W2, ws_scores);
    softmax_k<<<32, 256, 0, stream>>>(ws_scores, mask, out);
}

// Round 12
// 116.678 us; speedup vs baseline: 1.1625x; 1.1625x over previous
//
#include <hip/hip_runtime.h>
#include <hip/hip_bf16.h>
#include <cstdint>

// Problem: B=32, S=1024, H_IN=1024, H=1024
// scores[b,s] = sum_h tanh( enc[b,s,:]·W1_enc[h,:] + hidden[b,:]·W1_hid[h,:] + b1[h] ) * W2[h]
// out[b,0,s] = softmax_s( mask ? -inf : scores )    (b2 is softmax-shift-invariant)
//
// Round 12 (4 launches): prep_k + conv_k (r10-exact) -> gemm_s (SMALL-TILE TLP:
// BM=64 BN=128 BK=64, 24KB LDS, 6 blocks/CU, r10's plain 2-barrier gload_lds
// structure; ~2048 active blocks so the grid, not blocks/CU, no longer caps
// resident waves) -> softmax_k. Evidence: every deep-schedule variant at
// 1 blk/CU = 94-97us; gemm_c at 4 blk/CU = 77us; occupancy was grid-capped.

#define BK 64
#define NKT 16

typedef short  s16x8 __attribute__((ext_vector_type(8)));
typedef float  f32x4 __attribute__((ext_vector_type(4)));
typedef unsigned int u32;
typedef unsigned short u16;
typedef unsigned long long u64;

__device__ static inline u32 f2bf(float f) {            // f32 -> bf16 (RNE)
    u32 u = __float_as_uint(f);
    return (u + 0x7fffu + ((u >> 16) & 1u)) >> 16;
}
__device__ static inline u32 pk2(float a, float b) {
    return f2bf(a) | (f2bf(b) << 16);
}

__device__ static inline void gload_lds16(const void* g, void* l) {
    __builtin_amdgcn_global_load_lds(
        (const __attribute__((address_space(1))) u32*)g,
        (__attribute__((address_space(3))) u32*)l, 16, 0, 0);
}

// ---------------- prep: pack W1_enc (linear) + hv + mask compaction + zero scores ----------------
__global__ __launch_bounds__(256) void prep_k(const float* __restrict__ W1,
                                              const float* __restrict__ hidden,
                                              const float* __restrict__ b1,
                                              const void*  __restrict__ maskv,
                                              u16*   __restrict__ Wb,
                                              float* __restrict__ hv,
                                              int*   __restrict__ sidx,
                                              int*   __restrict__ cnt,
                                              float* __restrict__ scores) {
    const int bx = blockIdx.x, t = threadIdx.x;
    const int wid = t >> 6, lane = t & 63;
    __shared__ int sflag[4];

    if (bx < 512) {
        // pack W1_enc to bf16, LINEAR [n][k]
        const int i = bx * 256 + t;                    // 16B-out-chunk id, 0..131071
        const int n = i >> 7, gc = i & 127;
        const float4 v0 = *(const float4*)(W1 + (size_t)n * 2048 + gc * 8);
        const float4 v1 = *(const float4*)(W1 + (size_t)n * 2048 + gc * 8 + 4);
        uint4 o; o.x = pk2(v0.x, v0.y); o.y = pk2(v0.z, v0.w);
        o.z = pk2(v1.x, v1.y); o.w = pk2(v1.z, v1.w);
        *(uint4*)(Wb + (size_t)n * 1024 + gc * 8) = o;
    } else if (bx < 768) {
        // hv[b][h] = hidden[b,:]·W1_hid[h,:] + b1[h]
        const int h = (bx - 512) * 4 + wid;
        const float4* wrow = (const float4*)(W1 + (size_t)h * 2048 + 1024);
        float4 w[4];
#pragma unroll
        for (int q = 0; q < 4; q++) w[q] = wrow[lane + 64 * q];
        for (int b = 0; b < 32; b++) {
            const float4* hb = (const float4*)(hidden + (size_t)b * 1024);
            float p = 0.f;
#pragma unroll
            for (int q = 0; q < 4; q++) {
                float4 x = hb[lane + 64 * q];
                p = fmaf(w[q].x, x.x, fmaf(w[q].y, x.y, fmaf(w[q].z, x.z, fmaf(w[q].w, x.w, p))));
            }
#pragma unroll
            for (int off = 1; off < 64; off <<= 1) p += __shfl_xor(p, off);
            if (lane == 0) hv[(size_t)b * 1024 + h] = p + b1[h];
        }
    } else if (bx < 776) {
        // mask dtype detect + per-batch stable compaction of unmasked s
        const u32* mw = (const u32*)maskv;
        int f = 0;
#pragma unroll
        for (int j = 0; j < 32; j++) f |= (mw[t * 32 + j] > 1u) ? 1 : 0;
        const int anyf = __any(f);
        if (lane == 0) sflag[wid] = anyf;
        __syncthreads();
        const int bytemode = sflag[0] | sflag[1] | sflag[2] | sflag[3];

        const int b = (bx - 768) * 4 + wid;
        int base = 0;
        for (int c = 0; c < 16; c++) {
            const int s = c * 64 + lane;
            int m;
            if (bytemode) m = ((const unsigned char*)maskv)[(size_t)b * 1024 + s];
            else          m = ((const int*)maskv)[(size_t)b * 1024 + s];
            const u64 bal = __ballot(m == 0);
            if (m == 0) {
                const int off = (int)__popcll(bal & ((1ull << lane) - 1ull));
                sidx[(size_t)b * 1024 + base + off] = s;
            }
            base += (int)__popcll(bal);
        }
        if (lane == 0) cnt[b] = base;
        for (int j = base + lane; j < 1024; j += 64) sidx[(size_t)b * 1024 + j] = 0;
    } else {
        // zero scores
        const int i = (bx - 776) * 256 + t;
        ((float4*)scores)[i] = make_float4(0.f, 0.f, 0.f, 0.f);
    }
}

// ---------------- gather-convert compacted enc rows to bf16, LINEAR, 128-padded ----------------
// 8192 blocks, XCD-aligned to the gemm's batch->XCD map. 4 rows per block.
__global__ __launch_bounds__(256) void conv_k(const float* __restrict__ enc,
                                              const int* __restrict__ sidx,
                                              const int* __restrict__ cnt,
                                              u16* __restrict__ encC) {
    const int bid = blockIdx.x, t = threadIdx.x;
    const int xcd = bid & 7, w = bid >> 3;             // w 0..1023
    const int b = xcd * 4 + (w >> 8);                  // batches 4X..4X+3 on XCD X
    const int j0 = (w & 255) * 4;
    const int c = cnt[b];
    if (j0 >= ((c + 127) & ~127)) return;              // pad to 128 (>= any 64-tile range)
#pragma unroll
    for (int r = 0; r < 4; r++) {
        const int j = j0 + r;
        const int s = (j < c) ? sidx[(size_t)b * 1024 + j] : 0;
        const float4 v = ((const float4*)(enc + ((size_t)s * 32 + b) * 1024))[t];
        uint2 o; o.x = pk2(v.x, v.y); o.y = pk2(v.z, v.w);
        *(uint2*)(encC + ((size_t)b * 1024 + j) * 1024 + t * 4) = o;
    }
}

// ---------------- GEMM: small-tile (64x128), 6 blocks/CU, 2-barrier, fused epilogue ----------------
// 256 threads = 4 waves (wr 0..1 x wc 0..1); per-wave out 32x64 (acc[2][4]).
__global__ __launch_bounds__(256, 6) void gemm_s(
    const u16* __restrict__ encC,       // [32][1024][1024] bf16 (compacted rows)
    const u16* __restrict__ Wb,         // [1024][1024] bf16
    const int* __restrict__ sidx,
    const int* __restrict__ cnt,
    const float* __restrict__ hv,
    const float* __restrict__ W2,
    float*      __restrict__ scores)    // [32][1024] f32, pre-zeroed, atomics
{
    __shared__ u16 As[64 * BK];         // 8 KB
    __shared__ u16 Bs[128 * BK];        // 16 KB   (24 KB -> 6 blocks/CU)

    const int tid = threadIdx.x;
    const int bid = blockIdx.x;         // 4096 blocks
    // XCD map (bijective, 4096 = 8*512): batches [4X,4X+4) on XCD X (conv-aligned);
    // 8 nt of one (b,mt) strip stay on one XCD.
    const int xcd = bid & 7, idx = bid >> 3;           // idx 0..511
    const int strip = xcd * 64 + (idx >> 3);           // 0..511 = b*16+mt
    const int nt = idx & 7;
    const int b = strip >> 4, mt = strip & 15;
    const int c = cnt[b];
    if (mt * 64 >= c) return;

    // staging: chunk idx -> row = chunk>>3, c16 = chunk&7 (16B units)
    const int srow = tid >> 3, sc16 = tid & 7;         // srow 0..31
    const u16* asrc = encC + ((size_t)b * 1024 + mt * 64 + srow) * 1024 + sc16 * 8;
    const u16* bsrc = Wb + ((size_t)(nt * 128) + srow) * 1024 + sc16 * 8;

    const int wid = tid >> 6, lane = tid & 63;
    const int wr = wid >> 1, wc = wid & 1;
    const int lhi = lane >> 4, llo = lane & 15;

    f32x4 acc[2][4] = {};

    for (int kt = 0; kt < NKT; kt++) {
        const size_t ko = (size_t)kt * 64;
#pragma unroll
        for (int j = 0; j < 2; j++)                    // A: 512 chunks
            gload_lds16(asrc + ko + (size_t)j * 32 * 1024, &As[(j * 256 + tid) * 8]);
#pragma unroll
        for (int j = 0; j < 4; j++)                    // B: 1024 chunks
            gload_lds16(bsrc + ko + (size_t)j * 32 * 1024, &Bs[(j * 256 + tid) * 8]);
        __syncthreads();
#pragma unroll
        for (int kk = 0; kk < 2; kk++) {
            s16x8 af[2], bfr[4];
#pragma unroll
            for (int f = 0; f < 2; f++)
                af[f] = *(const s16x8*)&As[(wr * 32 + f * 16 + llo) * BK + kk * 32 + lhi * 8];
#pragma unroll
            for (int f = 0; f < 4; f++)
                bfr[f] = *(const s16x8*)&Bs[(wc * 64 + f * 16 + llo) * BK + kk * 32 + lhi * 8];
#pragma unroll
            for (int fi = 0; fi < 2; fi++)
#pragma unroll
                for (int fj = 0; fj < 4; fj++)
                    acc[fi][fj] = __builtin_amdgcn_mfma_f32_16x16x32_bf16(af[fi], bfr[fj], acc[fi][fj], 0, 0, 0);
        }
        __syncthreads();
    }

    // epilogue: tanh(acc + hv) · w2, reduce over this block's 128 n-cols, scatter-atomic
    const float* hvb = hv + (size_t)b * 1024;
    float hvv[4], w2v[4];
#pragma unroll
    for (int fj = 0; fj < 4; fj++) {
        const int n = nt * 128 + wc * 64 + fj * 16 + llo;
        hvv[fj] = hvb[n];
        w2v[fj] = W2[n];
    }
#pragma unroll
    for (int fi = 0; fi < 2; fi++) {
#pragma unroll
        for (int r = 0; r < 4; r++) {
            float sum = 0.f;
#pragma unroll
            for (int fj = 0; fj < 4; fj++) {
                const float x = acc[fi][fj][r] + hvv[fj];
                const float e = __expf(2.f * x);
                const float t = 1.f - 2.f / (e + 1.f);   // tanh(x)
                sum = fmaf(t, w2v[fj], sum);
            }
            sum += __shfl_xor(sum, 1);
            sum += __shfl_xor(sum, 2);
            sum += __shfl_xor(sum, 4);
            sum += __shfl_xor(sum, 8);
            if (llo == 0) {
                const int j = mt * 64 + wr * 32 + fi * 16 + lhi * 4 + r;
                if (j < c) {
                    const int s = sidx[(size_t)b * 1024 + j];
                    atomicAdd(&scores[(size_t)b * 1024 + s], sum);
                }
            }
        }
    }
}

// ---------------- masked softmax per row b, mask dtype auto-detected ----------------
__global__ __launch_bounds__(256) void softmax_k(const float* __restrict__ scores,
                                                 const void* __restrict__ maskv,
                                                 float* __restrict__ out) {
    const int b = blockIdx.x, t = threadIdx.x;
    const int wid = t >> 6, lane = t & 63;
    const u32* mw = (const u32*)maskv;
    int f = 0;
#pragma unroll
    for (int j = 0; j < 32; j++) f |= (mw[t * 32 + j] > 1u) ? 1 : 0;
    __shared__ int sflag[4];
    const int anyf = __any(f);
    if (lane == 0) sflag[wid] = anyf;
    __syncthreads();
    const int bytemode = sflag[0] | sflag[1] | sflag[2] | sflag[3];

    int m0, m1, m2, m3;
    if (bytemode) {
        const uchar4 mk = ((const uchar4*)((const unsigned char*)maskv + (size_t)b * 1024))[t];
        m0 = mk.x; m1 = mk.y; m2 = mk.z; m3 = mk.w;
    } else {
        const int4 mk = ((const int4*)((const int*)maskv + (size_t)b * 1024))[t];
        m0 = mk.x; m1 = mk.y; m2 = mk.z; m3 = mk.w;
    }
    const float4 sc = ((const float4*)(scores + (size_t)b * 1024))[t];
    const float v0 = m0 ? -1e30f : sc.x;
    const float v1 = m1 ? -1e30f : sc.y;
    const float v2 = m2 ? -1e30f : sc.z;
    const float v3 = m3 ? -1e30f : sc.w;
    float mx = fmaxf(fmaxf(v0, v1), fmaxf(v2, v3));
#pragma unroll
    for (int off = 1; off < 64; off <<= 1) mx = fmaxf(mx, __shfl_xor(mx, off));
    __shared__ float redm[4], reds[4];
    if (lane == 0) redm[wid] = mx;
    __syncthreads();
    mx = fmaxf(fmaxf(redm[0], redm[1]), fmaxf(redm[2], redm[3]));
    const float e0 = m0 ? 0.f : __expf(v0 - mx);
    const float e1 = m1 ? 0.f : __expf(v1 - mx);
    const float e2 = m2 ? 0.f : __expf(v2 - mx);
    const float e3 = m3 ? 0.f : __expf(v3 - mx);
    float s = e0 + e1 + e2 + e3;
#pragma unroll
    for (int off = 1; off < 64; off <<= 1) s += __shfl_xor(s, off);
    if (lane == 0) reds[wid] = s;
    __syncthreads();
    s = reds[0] + reds[1] + reds[2] + reds[3];
    const float inv = 1.f / s;
    float4 o; o.x = e0 * inv; o.y = e1 * inv; o.z = e2 * inv; o.w = e3 * inv;
    ((float4*)(out + (size_t)b * 1024))[t] = o;
}

extern "C" void kernel_launch(void* const* d_in, const int* in_sizes, int n_in,
                              void* d_out, int out_size, void* d_ws, size_t ws_size,
                              hipStream_t stream) {
    const float* hidden = (const float*)d_in[0];
    const float* enc    = (const float*)d_in[1];           // (S,B,H_IN) f32
    const void*  mask   = d_in[2];
    const float* W1 = (const float*)d_in[3];               // (H, H_IN+H) f32
    const float* b1 = (const float*)d_in[4];
    const float* W2 = (const float*)d_in[5];
    float* out = (float*)d_out;

    char* ws = (char*)d_ws;
    float* ws_scores = (float*)ws;                          // 128 KB
    float* ws_hv     = (float*)(ws + (128u << 10));         // 128 KB
    u16*   ws_Wb     = (u16*)(ws + (256u << 10));           // 2 MB
    int*   ws_cnt    = (int*)(ws + (2304u << 10));          // 128 B
    int*   ws_sidx   = (int*)(ws + (2432u << 10));          // 128 KB
    u16*   ws_encC   = (u16*)(ws + (4096u << 10));          // 64 MB

    prep_k<<<808, 256, 0, stream>>>(W1, hidden, b1, mask, ws_Wb, ws_hv, ws_sidx, ws_cnt, ws_scores);
    conv_k<<<8192, 256, 0, stream>>>(enc, ws_sidx, ws_cnt, ws_encC);
    gemm_s<<<4096, 256, 0, stream>>>(ws_encC, ws_Wb, ws_sidx, ws_cnt, ws_hv, W2, ws_scores);
    softmax_k<<<32, 256, 0, stream>>>(ws_scores, mask, out);
}

// Round 13
// 101.511 us; speedup vs baseline: 1.3362x; 1.1494x over previous
//
#include <hip/hip_runtime.h>
#include <hip/hip_bf16.h>
#include <cstdint>

// Problem: B=32, S=1024, H_IN=1024, H=1024
// scores[b,s] = sum_h tanh( enc[b,s,:]·W1_enc[h,:] + hidden[b,:]·W1_hid[h,:] + b1[h] ) * W2[h]
// out[b,0,s] = softmax_s( mask ? -inf : scores )    (b2 is softmax-shift-invariant)
//
// Round 13 (4 launches): r12 EXACTLY, single change = T2 swizzle on the gemm LDS
// tiles (sources pre-swizzled in prep/conv, staging stays linear gload_lds,
// ds_read applies the XOR; formula pair proven in r4/r7 with conflicts=0).
// r12 located the wall: ~54/79us of gemm_s is LDS-pipe time, 33us of it the
// 16-way read conflict (2.03e7 cycles). High-occupancy x zero-conflict is the
// one untried cell of the matrix.

#define BK 64
#define NKT 16

typedef short  s16x8 __attribute__((ext_vector_type(8)));
typedef float  f32x4 __attribute__((ext_vector_type(4)));
typedef unsigned int u32;
typedef unsigned short u16;
typedef unsigned long long u64;

__device__ static inline u32 f2bf(float f) {            // f32 -> bf16 (RNE)
    u32 u = __float_as_uint(f);
    return (u + 0x7fffu + ((u >> 16) & 1u)) >> 16;
}
__device__ static inline u32 pk2(float a, float b) {
    return f2bf(a) | (f2bf(b) << 16);
}

__device__ static inline void gload_lds16(const void* g, void* l) {
    __builtin_amdgcn_global_load_lds(
        (const __attribute__((address_space(1))) u32*)g,
        (__attribute__((address_space(3))) u32*)l, 16, 0, 0);
}

// ---------------- prep: pack W1_enc (SWIZZLED) + hv + mask compaction + zero scores ----------------
__global__ __launch_bounds__(256) void prep_k(const float* __restrict__ W1,
                                              const float* __restrict__ hidden,
                                              const float* __restrict__ b1,
                                              const void*  __restrict__ maskv,
                                              u16*   __restrict__ Wb,
                                              float* __restrict__ hv,
                                              int*   __restrict__ sidx,
                                              int*   __restrict__ cnt,
                                              float* __restrict__ scores) {
    const int bx = blockIdx.x, t = threadIdx.x;
    const int wid = t >> 6, lane = t & 63;
    __shared__ int sflag[4];

    if (bx < 512) {
        // pack W1_enc to bf16, swizzled: chunk gc -> (gc&~7)|((gc&7)^(n&7))
        const int i = bx * 256 + t;                    // 16B-out-chunk id, 0..131071
        const int n = i >> 7, gc = i & 127;
        const int p = (gc & ~7) | ((gc & 7) ^ (n & 7));
        const float4 v0 = *(const float4*)(W1 + (size_t)n * 2048 + gc * 8);
        const float4 v1 = *(const float4*)(W1 + (size_t)n * 2048 + gc * 8 + 4);
        uint4 o; o.x = pk2(v0.x, v0.y); o.y = pk2(v0.z, v0.w);
        o.z = pk2(v1.x, v1.y); o.w = pk2(v1.z, v1.w);
        *(uint4*)(Wb + (size_t)n * 1024 + p * 8) = o;
    } else if (bx < 768) {
        // hv[b][h] = hidden[b,:]·W1_hid[h,:] + b1[h]
        const int h = (bx - 512) * 4 + wid;
        const float4* wrow = (const float4*)(W1 + (size_t)h * 2048 + 1024);
        float4 w[4];
#pragma unroll
        for (int q = 0; q < 4; q++) w[q] = wrow[lane + 64 * q];
        for (int b = 0; b < 32; b++) {
            const float4* hb = (const float4*)(hidden + (size_t)b * 1024);
            float p = 0.f;
#pragma unroll
            for (int q = 0; q < 4; q++) {
                float4 x = hb[lane + 64 * q];
                p = fmaf(w[q].x, x.x, fmaf(w[q].y, x.y, fmaf(w[q].z, x.z, fmaf(w[q].w, x.w, p))));
            }
#pragma unroll
            for (int off = 1; off < 64; off <<= 1) p += __shfl_xor(p, off);
            if (lane == 0) hv[(size_t)b * 1024 + h] = p + b1[h];
        }
    } else if (bx < 776) {
        // mask dtype detect + per-batch stable compaction of unmasked s
        const u32* mw = (const u32*)maskv;
        int f = 0;
#pragma unroll
        for (int j = 0; j < 32; j++) f |= (mw[t * 32 + j] > 1u) ? 1 : 0;
        const int anyf = __any(f);
        if (lane == 0) sflag[wid] = anyf;
        __syncthreads();
        const int bytemode = sflag[0] | sflag[1] | sflag[2] | sflag[3];

        const int b = (bx - 768) * 4 + wid;
        int base = 0;
        for (int c = 0; c < 16; c++) {
            const int s = c * 64 + lane;
            int m;
            if (bytemode) m = ((const unsigned char*)maskv)[(size_t)b * 1024 + s];
            else          m = ((const int*)maskv)[(size_t)b * 1024 + s];
            const u64 bal = __ballot(m == 0);
            if (m == 0) {
                const int off = (int)__popcll(bal & ((1ull << lane) - 1ull));
                sidx[(size_t)b * 1024 + base + off] = s;
            }
            base += (int)__popcll(bal);
        }
        if (lane == 0) cnt[b] = base;
        for (int j = base + lane; j < 1024; j += 64) sidx[(size_t)b * 1024 + j] = 0;
    } else {
        // zero scores
        const int i = (bx - 776) * 256 + t;
        ((float4*)scores)[i] = make_float4(0.f, 0.f, 0.f, 0.f);
    }
}

// ---------------- gather-convert compacted enc rows to bf16, SWIZZLED, 128-padded ----------------
// 8192 blocks, XCD-aligned to the gemm's batch->XCD map. 4 rows per block.
__global__ __launch_bounds__(256) void conv_k(const float* __restrict__ enc,
                                              const int* __restrict__ sidx,
                                              const int* __restrict__ cnt,
                                              u16* __restrict__ encC) {
    const int bid = blockIdx.x, t = threadIdx.x;
    const int xcd = bid & 7, w = bid >> 3;             // w 0..1023
    const int b = xcd * 4 + (w >> 8);                  // batches 4X..4X+3 on XCD X
    const int j0 = (w & 255) * 4;
    const int c = cnt[b];
    if (j0 >= ((c + 127) & ~127)) return;              // pad to 128 (>= any 64-tile range)
    const int gc = t >> 1, h = t & 1;                  // 16B chunk, half
#pragma unroll
    for (int r = 0; r < 4; r++) {
        const int j = j0 + r;
        const int s = (j < c) ? sidx[(size_t)b * 1024 + j] : 0;
        const float4 v = ((const float4*)(enc + ((size_t)s * 32 + b) * 1024))[t];
        const int p = (gc & ~7) | ((gc & 7) ^ (j & 7));    // swizzle within K-segment
        uint2 o; o.x = pk2(v.x, v.y); o.y = pk2(v.z, v.w);
        *(uint2*)(encC + ((size_t)b * 1024 + j) * 1024 + p * 8 + h * 4) = o;
    }
}

// ---------------- GEMM: small-tile (64x128), 6 blocks/CU, 2-barrier, swizzled LDS ----------------
// 256 threads = 4 waves (wr 0..1 x wc 0..1); per-wave out 32x64 (acc[2][4]).
__global__ __launch_bounds__(256, 6) void gemm_s(
    const u16* __restrict__ encC,       // [32][1024][1024] bf16, swizzled rows
    const u16* __restrict__ Wb,         // [1024][1024] bf16, swizzled rows
    const int* __restrict__ sidx,
    const int* __restrict__ cnt,
    const float* __restrict__ hv,
    const float* __restrict__ W2,
    float*      __restrict__ scores)    // [32][1024] f32, pre-zeroed, atomics
{
    __shared__ u16 As[64 * BK];         // 8 KB
    __shared__ u16 Bs[128 * BK];        // 16 KB   (24 KB -> 6 blocks/CU)

    const int tid = threadIdx.x;
    const int bid = blockIdx.x;         // 4096 blocks
    // XCD map (bijective, 4096 = 8*512): batches [4X,4X+4) on XCD X (conv-aligned);
    // 8 nt of one (b,mt) strip stay on one XCD.
    const int xcd = bid & 7, idx = bid >> 3;           // idx 0..511
    const int strip = xcd * 64 + (idx >> 3);           // 0..511 = b*16+mt
    const int nt = idx & 7;
    const int b = strip >> 4, mt = strip & 15;
    const int c = cnt[b];
    if (mt * 64 >= c) return;

    // staging: chunk idx -> row = chunk>>3, c16 = chunk&7 (16B units); LINEAR
    // (sources pre-swizzled, so LDS holds the swizzled layout)
    const int srow = tid >> 3, sc16 = tid & 7;         // srow 0..31
    const u16* asrc = encC + ((size_t)b * 1024 + mt * 64 + srow) * 1024 + sc16 * 8;
    const u16* bsrc = Wb + ((size_t)(nt * 128) + srow) * 1024 + sc16 * 8;

    const int wid = tid >> 6, lane = tid & 63;
    const int wr = wid >> 1, wc = wid & 1;
    const int lhi = lane >> 4, llo = lane & 15;

    f32x4 acc[2][4] = {};

    for (int kt = 0; kt < NKT; kt++) {
        const size_t ko = (size_t)kt * 64;
#pragma unroll
        for (int j = 0; j < 2; j++)                    // A: 512 chunks
            gload_lds16(asrc + ko + (size_t)j * 32 * 1024, &As[(j * 256 + tid) * 8]);
#pragma unroll
        for (int j = 0; j < 4; j++)                    // B: 1024 chunks
            gload_lds16(bsrc + ko + (size_t)j * 32 * 1024, &Bs[(j * 256 + tid) * 8]);
        __syncthreads();
#pragma unroll
        for (int kk = 0; kk < 2; kk++) {
            s16x8 af[2], bfr[4];
#pragma unroll
            for (int f = 0; f < 2; f++) {
                const int row = wr * 32 + f * 16 + llo;
                const int ph = (kk * 4 + lhi) ^ (llo & 7);
                af[f] = *(const s16x8*)&As[row * BK + ph * 8];
            }
#pragma unroll
            for (int f = 0; f < 4; f++) {
                const int row = wc * 64 + f * 16 + llo;
                const int ph = (kk * 4 + lhi) ^ (llo & 7);
                bfr[f] = *(const s16x8*)&Bs[row * BK + ph * 8];
            }
#pragma unroll
            for (int fi = 0; fi < 2; fi++)
#pragma unroll
                for (int fj = 0; fj < 4; fj++)
                    acc[fi][fj] = __builtin_amdgcn_mfma_f32_16x16x32_bf16(af[fi], bfr[fj], acc[fi][fj], 0, 0, 0);
        }
        __syncthreads();
    }

    // epilogue: tanh(acc + hv) · w2, reduce over this block's 128 n-cols, scatter-atomic
    const float* hvb = hv + (size_t)b * 1024;
    float hvv[4], w2v[4];
#pragma unroll
    for (int fj = 0; fj < 4; fj++) {
        const int n = nt * 128 + wc * 64 + fj * 16 + llo;
        hvv[fj] = hvb[n];
        w2v[fj] = W2[n];
    }
#pragma unroll
    for (int fi = 0; fi < 2; fi++) {
#pragma unroll
        for (int r = 0; r < 4; r++) {
            float sum = 0.f;
#pragma unroll
            for (int fj = 0; fj < 4; fj++) {
                const float x = acc[fi][fj][r] + hvv[fj];
                const float e = __expf(2.f * x);
                const float t = 1.f - 2.f / (e + 1.f);   // tanh(x)
                sum = fmaf(t, w2v[fj], sum);
            }
            sum += __shfl_xor(sum, 1);
            sum += __shfl_xor(sum, 2);
            sum += __shfl_xor(sum, 4);
            sum += __shfl_xor(sum, 8);
            if (llo == 0) {
                const int j = mt * 64 + wr * 32 + fi * 16 + lhi * 4 + r;
                if (j < c) {
                    const int s = sidx[(size_t)b * 1024 + j];
                    atomicAdd(&scores[(size_t)b * 1024 + s], sum);
                }
            }
        }
    }
}

// ---------------- masked softmax per row b, mask dtype auto-detected ----------------
__global__ __launch_bounds__(256) void softmax_k(const float* __restrict__ scores,
                                                 const void* __restrict__ maskv,
                                                 float* __restrict__ out) {
    const int b = blockIdx.x, t = threadIdx.x;
    const int wid = t >> 6, lane = t & 63;
    const u32* mw = (const u32*)maskv;
    int f = 0;
#pragma unroll
    for (int j = 0; j < 32; j++) f |= (mw[t * 32 + j] > 1u) ? 1 : 0;
    __shared__ int sflag[4];
    const int anyf = __any(f);
    if (lane == 0) sflag[wid] = anyf;
    __syncthreads();
    const int bytemode = sflag[0] | sflag[1] | sflag[2] | sflag[3];

    int m0, m1, m2, m3;
    if (bytemode) {
        const uchar4 mk = ((const uchar4*)((const unsigned char*)maskv + (size_t)b * 1024))[t];
        m0 = mk.x; m1 = mk.y; m2 = mk.z; m3 = mk.w;
    } else {
        const int4 mk = ((const int4*)((const int*)maskv + (size_t)b * 1024))[t];
        m0 = mk.x; m1 = mk.y; m2 = mk.z; m3 = mk.w;
    }
    const float4 sc = ((const float4*)(scores + (size_t)b * 1024))[t];
    const float v0 = m0 ? -1e30f : sc.x;
    const float v1 = m1 ? -1e30f : sc.y;
    const float v2 = m2 ? -1e30f : sc.z;
    const float v3 = m3 ? -1e30f : sc.w;
    float mx = fmaxf(fmaxf(v0, v1), fmaxf(v2, v3));
#pragma unroll
    for (int off = 1; off < 64; off <<= 1) mx = fmaxf(mx, __shfl_xor(mx, off));
    __shared__ float redm[4], reds[4];
    if (lane == 0) redm[wid] = mx;
    __syncthreads();
    mx = fmaxf(fmaxf(redm[0], redm[1]), fmaxf(redm[2], redm[3]));
    const float e0 = m0 ? 0.f : __expf(v0 - mx);
    const float e1 = m1 ? 0.f : __expf(v1 - mx);
    const float e2 = m2 ? 0.f : __expf(v2 - mx);
    const float e3 = m3 ? 0.f : __expf(v3 - mx);
    float s = e0 + e1 + e2 + e3;
#pragma unroll
    for (int off = 1; off < 64; off <<= 1) s += __shfl_xor(s, off);
    if (lane == 0) reds[wid] = s;
    __syncthreads();
    s = reds[0] + reds[1] + reds[2] + reds[3];
    const float inv = 1.f / s;
    float4 o; o.x = e0 * inv; o.y = e1 * inv; o.z = e2 * inv; o.w = e3 * inv;
    ((float4*)(out + (size_t)b * 1024))[t] = o;
}

extern "C" void kernel_launch(void* const* d_in, const int* in_sizes, int n_in,
                              void* d_out, int out_size, void* d_ws, size_t ws_size,
                              hipStream_t stream) {
    const float* hidden = (const float*)d_in[0];
    const float* enc    = (const float*)d_in[1];           // (S,B,H_IN) f32
    const void*  mask   = d_in[2];
    const float* W1 = (const float*)d_in[3];               // (H, H_IN+H) f32
    const float* b1 = (const float*)d_in[4];
    const float* W2 = (const float*)d_in[5];
    float* out = (float*)d_out;

    char* ws = (char*)d_ws;
    float* ws_scores = (float*)ws;                          // 128 KB
    float* ws_hv     = (float*)(ws + (128u << 10));         // 128 KB
    u16*   ws_Wb     = (u16*)(ws + (256u << 10));           // 2 MB
    int*   ws_cnt    = (int*)(ws + (2304u << 10));          // 128 B
    int*   ws_sidx   = (int*)(ws + (2432u << 10));          // 128 KB
    u16*   ws_encC   = (u16*)(ws + (4096u << 10));          // 64 MB

    prep_k<<<808, 256, 0, stream>>>(W1, hidden, b1, mask, ws_Wb, ws_hv, ws_sidx, ws_cnt, ws_scores);
    conv_k<<<8192, 256, 0, stream>>>(enc, ws_sidx, ws_cnt, ws_encC);
    gemm_s<<<4096, 256, 0, stream>>>(ws_encC, ws_Wb, ws_sidx, ws_cnt, ws_hv, W2, ws_scores);
    softmax_k<<<32, 256, 0, stream>>>(ws_scores, mask, out);
}